// Round 1
// baseline (636.032 us; speedup 1.0000x reference)
//
#include <hip/hip_runtime.h>
#include <math.h>

#define F_IN 128
#define HID  16
#define NCLS 10

// ---------------- degree + dinv ----------------
__global__ void k_deg(const int* __restrict__ col, float* __restrict__ deg, int E) {
    int t = blockIdx.x * blockDim.x + threadIdx.x;
    if (t < E) atomicAdd(&deg[col[t]], 1.0f);
}

__global__ void k_dinv(float* __restrict__ deg, int N) {
    int t = blockIdx.x * blockDim.x + threadIdx.x;
    if (t < N) deg[t] = rsqrtf(deg[t] + 1.0f);   // +1 self loop; always > 0
}

// ---------------- xw = x @ W1  (128 -> 16) ----------------
// block = 256 threads, handles 16 nodes. W1 (8KB) + 16 x-rows (8KB+pad) in LDS.
__global__ void k_xw(const float* __restrict__ x, const float* __restrict__ W1,
                     float* __restrict__ xw, int N) {
    __shared__ float Ws[F_IN * HID];
    __shared__ float xs[16 * (F_IN + 1)];
    int t = threadIdx.x;
    for (int i = t; i < F_IN * HID; i += 256) Ws[i] = W1[i];
    int base = blockIdx.x * 16;
    if (base + 16 <= N) {
        for (int i = t; i < 16 * F_IN; i += 256) {
            int n = i >> 7, k = i & (F_IN - 1);
            xs[n * (F_IN + 1) + k] = x[(size_t)(base + n) * F_IN + k];
        }
    } else {
        for (int i = t; i < 16 * F_IN; i += 256) {
            int n = i >> 7, k = i & (F_IN - 1);
            xs[n * (F_IN + 1) + k] = (base + n < N) ? x[(size_t)(base + n) * F_IN + k] : 0.f;
        }
    }
    __syncthreads();
    int n = t >> 4, h = t & 15;
    if (base + n >= N) return;
    const float* xr = xs + n * (F_IN + 1);
    float acc = 0.f;
    #pragma unroll
    for (int k = 0; k < F_IN; ++k) acc += xr[k] * Ws[k * HID + h];
    xw[(size_t)(base + n) * HID + h] = acc;
}

// ---------------- layer-1 aggregation ----------------
__global__ void k_init1(const float* __restrict__ dinv, const float* __restrict__ xw,
                        float* __restrict__ agg, int N) {
    int t = blockIdx.x * blockDim.x + threadIdx.x;
    if (t < N * HID) {
        float d = dinv[t >> 4];
        agg[t] = d * d * xw[t];
    }
}

__global__ void k_scatter1(const int* __restrict__ row, const int* __restrict__ col,
                           const float* __restrict__ dinv, const float* __restrict__ xw,
                           float* __restrict__ agg, int E) {
    int t = blockIdx.x * blockDim.x + threadIdx.x;
    if (t >= E * HID) return;                 // 51.2M < 2^31
    int e = t >> 4, h = t & 15;
    int r = row[e], c = col[e];
    float w = dinv[r] * dinv[c];
    atomicAdd(&agg[(size_t)c * HID + h], w * xw[(size_t)r * HID + h]);
}

// ---------------- h = relu(agg1 + b1); hw = h @ W2 ----------------
__global__ void k_hw(const float* __restrict__ agg1, const float* __restrict__ b1,
                     const float* __restrict__ W2, float* __restrict__ hw, int N) {
    int n = blockIdx.x * blockDim.x + threadIdx.x;
    if (n >= N) return;
    float h[HID];
    #pragma unroll
    for (int j = 0; j < HID; ++j) {
        float v = agg1[(size_t)n * HID + j] + b1[j];
        h[j] = v > 0.f ? v : 0.f;
    }
    #pragma unroll
    for (int c = 0; c < NCLS; ++c) {
        float acc = 0.f;
        #pragma unroll
        for (int j = 0; j < HID; ++j) acc += h[j] * W2[j * NCLS + c];
        hw[(size_t)n * NCLS + c] = acc;
    }
}

// ---------------- layer-2 aggregation ----------------
__global__ void k_init2(const float* __restrict__ dinv, const float* __restrict__ hw,
                        float* __restrict__ agg, int N) {
    int t = blockIdx.x * blockDim.x + threadIdx.x;
    if (t < N * NCLS) {
        int n = t / NCLS;
        float d = dinv[n];
        agg[t] = d * d * hw[t];
    }
}

__global__ void k_scatter2(const int* __restrict__ row, const int* __restrict__ col,
                           const float* __restrict__ dinv, const float* __restrict__ hw,
                           float* __restrict__ agg, int E) {
    int t = blockIdx.x * blockDim.x + threadIdx.x;
    if (t >= E * NCLS) return;                // 32M
    int e = t / NCLS;
    int cc = t - e * NCLS;
    int r = row[e], c = col[e];
    float w = dinv[r] * dinv[c];
    atomicAdd(&agg[(size_t)c * NCLS + cc], w * hw[(size_t)r * NCLS + cc]);
}

// ---------------- logits + b2 -> log_softmax ----------------
__global__ void k_out(const float* __restrict__ agg2, const float* __restrict__ b2,
                      float* __restrict__ out, int N) {
    int n = blockIdx.x * blockDim.x + threadIdx.x;
    if (n >= N) return;
    float v[NCLS];
    float m = -INFINITY;
    #pragma unroll
    for (int c = 0; c < NCLS; ++c) {
        v[c] = agg2[(size_t)n * NCLS + c] + b2[c];
        m = fmaxf(m, v[c]);
    }
    float s = 0.f;
    #pragma unroll
    for (int c = 0; c < NCLS; ++c) s += __expf(v[c] - m);
    float lse = m + __logf(s);
    #pragma unroll
    for (int c = 0; c < NCLS; ++c) out[(size_t)n * NCLS + c] = v[c] - lse;
}

extern "C" void kernel_launch(void* const* d_in, const int* in_sizes, int n_in,
                              void* d_out, int out_size, void* d_ws, size_t ws_size,
                              hipStream_t stream) {
    const float* x  = (const float*)d_in[0];
    const int*   ei = (const int*)d_in[1];   // harness: integer inputs -> int32
    const float* W1 = (const float*)d_in[2];
    const float* b1 = (const float*)d_in[3];
    const float* W2 = (const float*)d_in[4];
    const float* b2 = (const float*)d_in[5];
    float* out = (float*)d_out;

    const int N = in_sizes[0] / F_IN;        // 100000
    const int E = in_sizes[1] / 2;           // 3200000
    const int* row = ei;                     // edge_index[0] = source
    const int* col = ei + E;                 // edge_index[1] = target

    char* ws = (char*)d_ws;
    auto alignup = [](size_t v) { return (v + 255) & ~(size_t)255; };
    size_t off = 0;
    float* deg  = (float*)(ws + off); off += alignup((size_t)N * 4);            // -> dinv in place
    float* xw   = (float*)(ws + off); off += alignup((size_t)N * HID * 4);
    float* agg1 = (float*)(ws + off); off += alignup((size_t)N * HID * 4);
    float* hw   = (float*)(ws + off); off += alignup((size_t)N * NCLS * 4);
    float* agg2 = (float*)(ws + off); off += alignup((size_t)N * NCLS * 4);
    (void)ws_size; (void)n_in; (void)out_size;

    hipMemsetAsync(deg, 0, (size_t)N * sizeof(float), stream);
    k_deg   <<<(E + 255) / 256, 256, 0, stream>>>(col, deg, E);
    k_dinv  <<<(N + 255) / 256, 256, 0, stream>>>(deg, N);
    k_xw    <<<(N + 15) / 16, 256, 0, stream>>>(x, W1, xw, N);
    k_init1 <<<(N * HID + 255) / 256, 256, 0, stream>>>(deg, xw, agg1, N);
    k_scatter1<<<(int)(((size_t)E * HID + 255) / 256), 256, 0, stream>>>(row, col, deg, xw, agg1, E);
    k_hw    <<<(N + 255) / 256, 256, 0, stream>>>(agg1, b1, W2, hw, N);
    k_init2 <<<(N * NCLS + 255) / 256, 256, 0, stream>>>(deg, hw, agg2, N);
    k_scatter2<<<(int)(((size_t)E * NCLS + 255) / 256), 256, 0, stream>>>(row, col, deg, hw, agg2, E);
    k_out   <<<(N + 255) / 256, 256, 0, stream>>>(agg2, b2, out, N);
}

// Round 2
// 466.615 us; speedup vs baseline: 1.3631x; 1.3631x over previous
//
#include <hip/hip_runtime.h>
#include <math.h>

#define F_IN 128
#define HID  16
#define NCLS 10

// ---------------- int degree histogram ----------------
__global__ void k_hist(const int* __restrict__ col, int* __restrict__ cnt, int E) {
    int t = blockIdx.x * blockDim.x + threadIdx.x;
    if (t < E) atomicAdd(&cnt[col[t]], 1);
}

__global__ void k_dinv(const int* __restrict__ cnt, float* __restrict__ dinv, int N) {
    int t = blockIdx.x * blockDim.x + threadIdx.x;
    if (t < N) dinv[t] = rsqrtf((float)cnt[t] + 1.0f);   // +1 self loop
}

// ---------------- xw_s = dinv[n] * (x @ W1)  (128 -> 16) ----------------
__global__ void k_xw(const float* __restrict__ x, const float* __restrict__ W1,
                     const float* __restrict__ dinv, float* __restrict__ xws, int N) {
    __shared__ float Ws[F_IN * HID];
    __shared__ float xs[16 * (F_IN + 1)];
    int t = threadIdx.x;
    for (int i = t; i < F_IN * HID; i += 256) Ws[i] = W1[i];
    int base = blockIdx.x * 16;
    for (int i = t; i < 16 * F_IN; i += 256) {
        int n = i >> 7, k = i & (F_IN - 1);
        xs[n * (F_IN + 1) + k] = (base + n < N) ? x[(size_t)(base + n) * F_IN + k] : 0.f;
    }
    __syncthreads();
    int n = t >> 4, h = t & 15;
    if (base + n >= N) return;
    const float* xr = xs + n * (F_IN + 1);
    float acc = 0.f;
    #pragma unroll
    for (int k = 0; k < F_IN; ++k) acc += xr[k] * Ws[k * HID + h];
    xws[(size_t)(base + n) * HID + h] = dinv[base + n] * acc;
}

// ---------------- exclusive scan over cnt -> off (3 kernels) ----------------
// scanA: 1024 elems/block (256 thr x 4), local exclusive scan -> off, block sum -> bsum
__global__ void k_scanA(const int* __restrict__ cnt, int* __restrict__ off,
                        int* __restrict__ bsum, int N) {
    __shared__ int s[256];
    int b = blockIdx.x, t = threadIdx.x;
    int base = b * 1024 + t * 4;
    int v[4], sum = 0;
    #pragma unroll
    for (int i = 0; i < 4; ++i) { int idx = base + i; v[i] = (idx < N) ? cnt[idx] : 0; sum += v[i]; }
    s[t] = sum;
    __syncthreads();
    for (int ofs = 1; ofs < 256; ofs <<= 1) {
        int val = 0;
        if (t >= ofs) val = s[t - ofs];
        __syncthreads();
        if (t >= ofs) s[t] += val;
        __syncthreads();
    }
    int excl = s[t] - sum;
    if (t == 255) bsum[b] = s[255];
    int run = excl;
    #pragma unroll
    for (int i = 0; i < 4; ++i) { int idx = base + i; if (idx < N) off[idx] = run; run += v[i]; }
}

__global__ void k_scanB(int* __restrict__ bsum, int nb) {
    __shared__ int s[128];
    int t = threadIdx.x;
    int v = (t < nb) ? bsum[t] : 0;
    s[t] = v;
    __syncthreads();
    for (int ofs = 1; ofs < 128; ofs <<= 1) {
        int val = 0;
        if (t >= ofs) val = s[t - ofs];
        __syncthreads();
        if (t >= ofs) s[t] += val;
        __syncthreads();
    }
    if (t < nb) bsum[t] = s[t] - v;   // exclusive
}

__global__ void k_scanC(int* __restrict__ off, const int* __restrict__ bsum, int N, int E) {
    int i = blockIdx.x * blockDim.x + threadIdx.x;
    if (i < N) off[i] += bsum[i >> 10];
    if (i == 0) off[N] = E;
}

// ---------------- fill CSR: srow[off[c] + cursor] = row ----------------
__global__ void k_fill(const int* __restrict__ row, const int* __restrict__ col,
                       const int* __restrict__ off, int* __restrict__ cur,
                       int* __restrict__ srow, int E) {
    int e = blockIdx.x * blockDim.x + threadIdx.x;
    if (e < E) {
        int c = col[e];
        int p = off[c] + atomicAdd(&cur[c], 1);
        srow[p] = row[e];
    }
}

// ---------------- layer-1 pull-gather: hs = dinv * relu(dinv*(sum) + b1) --------
__global__ void k_agg1(const float* __restrict__ xws, const int* __restrict__ off,
                       const int* __restrict__ srow, const float* __restrict__ dinv,
                       const float* __restrict__ b1, float* __restrict__ hs, int N) {
    int n = (blockIdx.x * blockDim.x + threadIdx.x) >> 4;
    int l = threadIdx.x & 15;
    if (n >= N) return;
    int s = off[n], e = off[n + 1];
    float acc = xws[(size_t)n * HID + l];   // self loop (already dinv-scaled)
    int i = s;
    for (; i + 3 < e; i += 4) {
        int r0 = srow[i], r1 = srow[i + 1], r2 = srow[i + 2], r3 = srow[i + 3];
        acc += xws[r0 * HID + l] + xws[r1 * HID + l] + xws[r2 * HID + l] + xws[r3 * HID + l];
    }
    for (; i < e; ++i) acc += xws[srow[i] * HID + l];
    float d = dinv[n];
    float h = d * acc + b1[l];
    h = h > 0.f ? h : 0.f;
    hs[(size_t)n * HID + l] = d * h;
}

// ---------------- layer-2 pull-gather + fused W2/b2/log_softmax ----------------
__global__ void k_agg2(const float* __restrict__ hs, const int* __restrict__ off,
                       const int* __restrict__ srow, const float* __restrict__ dinv,
                       const float* __restrict__ W2, const float* __restrict__ b2,
                       float* __restrict__ out, int N) {
    __shared__ float gs[16][17];
    __shared__ float W2s[HID * NCLS];
    __shared__ float b2s[NCLS];
    int t = threadIdx.x;
    if (t < HID * NCLS) W2s[t] = W2[t];
    if (t < NCLS) b2s[t] = b2[t];
    int grp = t >> 4, l = t & 15;
    int n = blockIdx.x * 16 + grp;
    float g = 0.f;
    if (n < N) {
        int s = off[n], e = off[n + 1];
        float acc = hs[(size_t)n * HID + l];
        int i = s;
        for (; i + 3 < e; i += 4) {
            int r0 = srow[i], r1 = srow[i + 1], r2 = srow[i + 2], r3 = srow[i + 3];
            acc += hs[r0 * HID + l] + hs[r1 * HID + l] + hs[r2 * HID + l] + hs[r3 * HID + l];
        }
        for (; i < e; ++i) acc += hs[srow[i] * HID + l];
        g = dinv[n] * acc;
    }
    gs[grp][l] = g;
    __syncthreads();
    if (t < 16) {
        int n2 = blockIdx.x * 16 + t;
        if (n2 < N) {
            float v[NCLS];
            float m = -INFINITY;
            #pragma unroll
            for (int c = 0; c < NCLS; ++c) {
                float a = b2s[c];
                #pragma unroll
                for (int j = 0; j < HID; ++j) a += gs[t][j] * W2s[j * NCLS + c];
                v[c] = a;
                m = fmaxf(m, a);
            }
            float ssum = 0.f;
            #pragma unroll
            for (int c = 0; c < NCLS; ++c) ssum += __expf(v[c] - m);
            float lse = m + __logf(ssum);
            #pragma unroll
            for (int c = 0; c < NCLS; ++c) out[(size_t)n2 * NCLS + c] = v[c] - lse;
        }
    }
}

extern "C" void kernel_launch(void* const* d_in, const int* in_sizes, int n_in,
                              void* d_out, int out_size, void* d_ws, size_t ws_size,
                              hipStream_t stream) {
    const float* x  = (const float*)d_in[0];
    const int*   ei = (const int*)d_in[1];
    const float* W1 = (const float*)d_in[2];
    const float* b1 = (const float*)d_in[3];
    const float* W2 = (const float*)d_in[4];
    const float* b2 = (const float*)d_in[5];
    float* out = (float*)d_out;

    const int N = in_sizes[0] / F_IN;        // 100000
    const int E = in_sizes[1] / 2;           // 3200000
    const int* row = ei;                     // source
    const int* col = ei + E;                 // target

    char* ws = (char*)d_ws;
    auto alignup = [](size_t v) { return (v + 255) & ~(size_t)255; };
    size_t offb = 0;
    int*   cnt  = (int*)  (ws + offb); offb += alignup((size_t)N * 4);          // hist -> cursor
    int*   off  = (int*)  (ws + offb); offb += alignup((size_t)(N + 1) * 4);
    int*   bsum = (int*)  (ws + offb); offb += alignup(1024 * 4);
    float* dinv = (float*)(ws + offb); offb += alignup((size_t)N * 4);
    int*   srow = (int*)  (ws + offb); offb += alignup((size_t)E * 4);
    float* xws  = (float*)(ws + offb); offb += alignup((size_t)N * HID * 4);
    float* hs   = (float*)(ws + offb); offb += alignup((size_t)N * HID * 4);
    (void)ws_size; (void)n_in; (void)out_size;

    const int nb = (N + 1023) / 1024;        // 98 (<=128 assumed)

    hipMemsetAsync(cnt, 0, (size_t)N * sizeof(int), stream);
    k_hist <<<(E + 255) / 256, 256, 0, stream>>>(col, cnt, E);
    k_dinv <<<(N + 255) / 256, 256, 0, stream>>>(cnt, dinv, N);
    k_xw   <<<(N + 15) / 16, 256, 0, stream>>>(x, W1, dinv, xws, N);
    k_scanA<<<nb, 256, 0, stream>>>(cnt, off, bsum, N);
    k_scanB<<<1, 128, 0, stream>>>(bsum, nb);
    k_scanC<<<(N + 255) / 256, 256, 0, stream>>>(off, bsum, N, E);
    hipMemsetAsync(cnt, 0, (size_t)N * sizeof(int), stream);
    k_fill <<<(E + 255) / 256, 256, 0, stream>>>(row, col, off, cnt, srow, E);
    k_agg1 <<<(N * HID + 255) / 256, 256, 0, stream>>>(xws, off, srow, dinv, b1, hs, N);
    k_agg2 <<<(N + 15) / 16, 256, 0, stream>>>(hs, off, srow, dinv, W2, b2, out, N);
}